// Round 1
// baseline (429.131 us; speedup 1.0000x reference)
//
#include <hip/hip_runtime.h>
#include <cstdint>
#include <cstddef>

// ---------- types ----------
typedef __attribute__((ext_vector_type(8))) __bf16 bf16x8;
typedef __attribute__((ext_vector_type(4))) float f32x4;
typedef __attribute__((ext_vector_type(4))) unsigned short u16x4;

__device__ __forceinline__ unsigned short f2bf(float f) {
  unsigned int u = __builtin_bit_cast(unsigned int, f);
  u += 0x7fffu + ((u >> 16) & 1u);           // RNE
  return (unsigned short)(u >> 16);
}

// ---------- weight cast + transpose: W[K][N] f32 -> WT[Npad][K] bf16 ----------
__global__ void wcast_t(const float* __restrict__ src, unsigned short* __restrict__ dst,
                        int K, int N, int Npad) {
  __shared__ float tile[32][33];
  int l = blockIdx.z;
  src += (size_t)l * K * N;
  dst += (size_t)l * (size_t)Npad * K;
  int n0 = blockIdx.x * 32, k0 = blockIdx.y * 32;
  int tx = threadIdx.x, ty = threadIdx.y;
#pragma unroll
  for (int i = ty; i < 32; i += 8) {
    int k = k0 + i, n = n0 + tx;
    tile[i][tx] = (n < N) ? src[(size_t)k * N + n] : 0.0f;
  }
  __syncthreads();
#pragma unroll
  for (int i = ty; i < 32; i += 8) {
    int n = n0 + i, k = k0 + tx;
    dst[(size_t)n * K + k] = f2bf(tile[tx][i]);
  }
}

// ---------- crop + *128 -> feats bf16 [256][4096] ----------
__global__ void crop_kernel(const float* __restrict__ x, const float* __restrict__ tr,
                            unsigned short* __restrict__ feats) {
  int b = blockIdx.x;
  __shared__ int xi[64], yi[64];
  float px = tr[b * 4 + 0], py = tr[b * 4 + 1], zx = tr[b * 4 + 2], zy = tr[b * 4 + 3];
  // exact-order f32 arithmetic (no fma contraction) to match numpy reference
  float x1 = __fmul_rn(px, 448.0f);
  float y1 = __fmul_rn(py, 448.0f);
  float xs = fminf(__fsub_rn(512.0f, x1), __fadd_rn(__fmul_rn(zx, 448.0f), 64.0f));
  float ys = fminf(__fsub_rn(512.0f, y1), __fadd_rn(__fmul_rn(zy, 448.0f), 64.0f));
  int t = threadIdx.x;
  if (t < 64) {
    float u = __fmul_rn(__fmul_rn((float)t, 0.015625f), xs);
    int v = (int)(__fadd_rn(floorf(u), x1));
    xi[t] = min(max(v, 0), 511);
  } else if (t < 128) {
    int tt = t - 64;
    float u = __fmul_rn(__fmul_rn((float)tt, 0.015625f), ys);
    int v = (int)(__fadd_rn(floorf(u), y1));
    yi[tt] = min(max(v, 0), 511);
  }
  __syncthreads();
  const float* img = x + (size_t)b * 262144;
  for (int p = t; p < 4096; p += 256) {
    int i = p >> 6, j = p & 63;
    float val = img[xi[i] * 512 + yi[j]] * 128.0f;
    feats[(size_t)b * 4096 + p] = f2bf(val);
  }
}

// ---------- z init: z[b][i][:] = history[i+1][b][:] for i<7 ----------
__global__ void zinit_kernel(const float* __restrict__ hist, float* __restrict__ z) {
  int idx = blockIdx.x * 256 + threadIdx.x;   // 458752 threads * 4 floats
  int off = idx * 4;
  int b = off / 7168;
  int r = off - b * 7168;
  int i = r >> 10, c = r & 1023;
  float4 v = *(const float4*)(hist + (size_t)(i + 1) * 262144 + (size_t)b * 1024 + c);
  *(float4*)(z + (size_t)b * 8192 + i * 1024 + c) = v;
}

// ---------- LayerNorm: z f32 [2048][1024] -> h bf16 (wave per row) ----------
__global__ __launch_bounds__(256) void ln_kernel(const float* __restrict__ z,
                                                 const float* __restrict__ sc,
                                                 const float* __restrict__ bi,
                                                 unsigned short* __restrict__ h) {
  int row = blockIdx.x * 4 + (threadIdx.x >> 6);
  int lane = threadIdx.x & 63;
  const float* zr = z + (size_t)row * 1024;
  float4 v[4];
  float s = 0.f, q = 0.f;
#pragma unroll
  for (int i = 0; i < 4; i++) {
    v[i] = *(const float4*)(zr + lane * 4 + i * 256);
    s += v[i].x + v[i].y + v[i].z + v[i].w;
    q += v[i].x * v[i].x + v[i].y * v[i].y + v[i].z * v[i].z + v[i].w * v[i].w;
  }
#pragma unroll
  for (int off = 32; off; off >>= 1) { s += __shfl_xor(s, off); q += __shfl_xor(q, off); }
  float mean = s * (1.0f / 1024.0f);
  float var = q * (1.0f / 1024.0f) - mean * mean;
  float rstd = rsqrtf(var + 1e-5f);
  u16x4* out = (u16x4*)(h + (size_t)row * 1024);
#pragma unroll
  for (int i = 0; i < 4; i++) {
    int c = lane * 4 + i * 256;
    float4 sv = *(const float4*)(sc + c);
    float4 bv = *(const float4*)(bi + c);
    u16x4 o;
    o.x = f2bf((v[i].x - mean) * rstd * sv.x + bv.x);
    o.y = f2bf((v[i].y - mean) * rstd * sv.y + bv.y);
    o.z = f2bf((v[i].z - mean) * rstd * sv.z + bv.z);
    o.w = f2bf((v[i].w - mean) * rstd * sv.w + bv.w);
    out[lane + i * 64] = o;
  }
}

// ---------- tiny attention: per (b,head), S=8, D=64 ----------
__global__ __launch_bounds__(64) void attn_kernel(const float* __restrict__ qkv,
                                                  unsigned short* __restrict__ obuf) {
  int bh = blockIdx.x;
  int b = bh >> 3, hh = bh & 7;
  const float* base = qkv + (size_t)b * 8 * 1536;
  __shared__ float Q[8][64], K[8][64], V[8][64], S[8][8], P[8][8];
  int t = threadIdx.x;
#pragma unroll
  for (int i = 0; i < 8; i++) {
    Q[i][t] = base[i * 1536 + hh * 64 + t];
    K[i][t] = base[i * 1536 + 512 + hh * 64 + t];
    V[i][t] = base[i * 1536 + 1024 + hh * 64 + t];
  }
  __syncthreads();
  {
    int i = t >> 3, j = t & 7;
    float s = 0.f;
#pragma unroll
    for (int d = 0; d < 64; d++) s += Q[i][d] * K[j][d];
    S[i][j] = s * 0.125f;
  }
  __syncthreads();
  {
    int i = t >> 3, j = t & 7;
    float m = S[i][0];
#pragma unroll
    for (int jj = 1; jj < 8; jj++) m = fmaxf(m, S[i][jj]);
    float sum = 0.f;
#pragma unroll
    for (int jj = 0; jj < 8; jj++) sum += expf(S[i][jj] - m);
    P[i][j] = expf(S[i][j] - m) / sum;
  }
  __syncthreads();
#pragma unroll
  for (int i = 0; i < 8; i++) {
    float o = 0.f;
#pragma unroll
    for (int j = 0; j < 8; j++) o += P[i][j] * V[j][t];
    obuf[(size_t)(b * 8 + i) * 512 + hh * 64 + t] = f2bf(o);
  }
}

// ---------- generic bf16 MFMA GEMM, 64x64 tile, BK=64, 4 waves ----------
__device__ __forceinline__ void stage_tile(const unsigned short* __restrict__ g, int ld,
                                           int k0, char* lbase, int tid) {
#pragma unroll
  for (int it = 0; it < 2; ++it) {
    int c = tid + it * 256;              // 16B chunk id, 512 per 64x64 bf16 tile
    int r = c >> 3;
    int c8 = (c & 7) ^ (r & 7);          // pre-swizzled global source (m173 pattern)
    const unsigned short* src = g + (size_t)r * ld + (k0 + c8 * 8);
    char* dst = lbase + c * 16;          // linear LDS dest: wave base + lane*16
    __builtin_amdgcn_global_load_lds((__attribute__((address_space(1))) void*)src,
                                     (__attribute__((address_space(3))) void*)dst, 16, 0, 0);
  }
}

__device__ __forceinline__ bf16x8 ld_frag(const char* base, int row, int k8) {
  int off = (row << 7) + ((k8 ^ (row & 7)) << 4);   // XOR swizzle (G4)
  return *(const bf16x8*)(base + off);
}

template <int ACT, bool OBF, bool RES>
__global__ __launch_bounds__(256) void gemm64(
    const unsigned short* __restrict__ A, const unsigned short* __restrict__ BT,
    const float* __restrict__ bias, const float* __restrict__ res,
    float* __restrict__ outF, unsigned short* __restrict__ outB,
    int K, int ldC, int Nstore) {
  __shared__ __align__(16) char smem[2][16384];
  const int tid = threadIdx.x;
  const int lane = tid & 63;
  const int wid = tid >> 6;
  const int wm = wid >> 1, wn = wid & 1;
  const int m0 = blockIdx.y << 6, n0 = blockIdx.x << 6;
  const unsigned short* Ag = A + (size_t)m0 * K;
  const unsigned short* Bg = BT + (size_t)n0 * K;
  f32x4 acc[2][2];
  acc[0][0] = 0.f; acc[0][1] = 0.f; acc[1][0] = 0.f; acc[1][1] = 0.f;
  const int nt = K >> 6;
  stage_tile(Ag, K, 0, smem[0], tid);
  stage_tile(Bg, K, 0, smem[0] + 8192, tid);
  __syncthreads();
  int cur = 0;
  const int rA = lane & 15, kq = lane >> 4;
  for (int t = 0; t < nt; ++t) {
    if (t + 1 < nt) {
      stage_tile(Ag, K, (t + 1) << 6, smem[cur ^ 1], tid);
      stage_tile(Bg, K, (t + 1) << 6, smem[cur ^ 1] + 8192, tid);
    }
    const char* la = smem[cur];
    const char* lb = smem[cur] + 8192;
#pragma unroll
    for (int kk = 0; kk < 2; ++kk) {
      bf16x8 a0 = ld_frag(la, wm * 32 + rA, kk * 4 + kq);
      bf16x8 a1 = ld_frag(la, wm * 32 + 16 + rA, kk * 4 + kq);
      bf16x8 b0 = ld_frag(lb, wn * 32 + rA, kk * 4 + kq);
      bf16x8 b1 = ld_frag(lb, wn * 32 + 16 + rA, kk * 4 + kq);
      acc[0][0] = __builtin_amdgcn_mfma_f32_16x16x32_bf16(a0, b0, acc[0][0], 0, 0, 0);
      acc[0][1] = __builtin_amdgcn_mfma_f32_16x16x32_bf16(a0, b1, acc[0][1], 0, 0, 0);
      acc[1][0] = __builtin_amdgcn_mfma_f32_16x16x32_bf16(a1, b0, acc[1][0], 0, 0, 0);
      acc[1][1] = __builtin_amdgcn_mfma_f32_16x16x32_bf16(a1, b1, acc[1][1], 0, 0, 0);
    }
    __syncthreads();
    cur ^= 1;
  }
  const int rb = m0 + wm * 32 + (kq << 2);
  const int cb = n0 + wn * 32 + rA;
#pragma unroll
  for (int m = 0; m < 2; m++)
#pragma unroll
    for (int n = 0; n < 2; n++) {
      int cg = cb + n * 16;
      if (cg >= Nstore) continue;
      float bv = bias ? bias[cg] : 0.0f;
#pragma unroll
      for (int j = 0; j < 4; j++) {
        int rg = rb + m * 16 + j;
        float v = acc[m][n][j] + bv;
        if (RES) v += res[(size_t)rg * ldC + cg];
        if (ACT == 1) v = 0.5f * v * (1.0f + erff(v * 0.70710678118654752f));
        if (OBF) outB[(size_t)rg * ldC + cg] = f2bf(v);
        else outF[(size_t)rg * ldC + cg] = v;
      }
    }
}

// ---------- z f32 -> bf16 cast ----------
__global__ void castz_kernel(const float* __restrict__ z, unsigned short* __restrict__ tl) {
  int i = blockIdx.x * 256 + threadIdx.x;   // x4 elements
  float4 v = *(const float4*)(z + (size_t)i * 4);
  u16x4 o;
  o.x = f2bf(v.x); o.y = f2bf(v.y); o.z = f2bf(v.z); o.w = f2bf(v.w);
  *(u16x4*)(tl + (size_t)i * 4) = o;
}

// ---------- transform head: sigmoid(z_flat @ w_tr + b_tr), N=4, K=8192 ----------
__global__ __launch_bounds__(256) void trhead_kernel(const float* __restrict__ z,
                                                     const float* __restrict__ w,
                                                     const float* __restrict__ bt,
                                                     float* __restrict__ out) {
  int b = blockIdx.x;
  int t = threadIdx.x;
  const float* row = z + (size_t)b * 8192;
  float a0 = 0.f, a1 = 0.f, a2 = 0.f, a3 = 0.f;
  for (int k = t; k < 8192; k += 256) {
    float xv = row[k];
    const float* wr = w + (size_t)k * 4;
    a0 += xv * wr[0]; a1 += xv * wr[1]; a2 += xv * wr[2]; a3 += xv * wr[3];
  }
  __shared__ float red[256][4];
  red[t][0] = a0; red[t][1] = a1; red[t][2] = a2; red[t][3] = a3;
  __syncthreads();
  for (int s = 128; s > 0; s >>= 1) {
    if (t < s) {
#pragma unroll
      for (int o = 0; o < 4; o++) red[t][o] += red[t + s][o];
    }
    __syncthreads();
  }
  if (t < 4) {
    float v = red[0][t] + bt[t];
    out[256000 + b * 4 + t] = 1.0f / (1.0f + expf(-v));
  }
}

// ---------- launch ----------
extern "C" void kernel_launch(void* const* d_in, const int* in_sizes, int n_in,
                              void* d_out, int out_size, void* d_ws, size_t ws_size,
                              hipStream_t stream) {
  const float* x      = (const float*)d_in[0];
  const float* tr     = (const float*)d_in[1];
  const float* hist   = (const float*)d_in[2];
  const float* w_img  = (const float*)d_in[3];
  const float* b_img  = (const float*)d_in[4];
  const float* ln1_s  = (const float*)d_in[5];
  const float* ln1_b  = (const float*)d_in[6];
  const float* w_qkv  = (const float*)d_in[7];
  const float* w_o    = (const float*)d_in[8];
  const float* b_o    = (const float*)d_in[9];
  const float* ln2_s  = (const float*)d_in[10];
  const float* ln2_b  = (const float*)d_in[11];
  const float* w_ff1  = (const float*)d_in[12];
  const float* b_ff1  = (const float*)d_in[13];
  const float* w_ff2  = (const float*)d_in[14];
  const float* b_ff2  = (const float*)d_in[15];
  const float* w_cls  = (const float*)d_in[16];
  const float* b_cls  = (const float*)d_in[17];
  const float* w_tr   = (const float*)d_in[18];
  const float* b_tr   = (const float*)d_in[19];
  float* outF = (float*)d_out;

  // workspace carve (all sizes multiples of 256B); ~92.3 MB total
  char* w = (char*)d_ws;
  auto alloc = [&](size_t bytes) { char* p = w; w += (bytes + 255) & ~(size_t)255; return p; };
  unsigned short* BT_img = (unsigned short*)alloc((size_t)1024 * 4096 * 2);
  unsigned short* BT_qkv = (unsigned short*)alloc((size_t)4 * 1536 * 1024 * 2);
  unsigned short* BT_o   = (unsigned short*)alloc((size_t)4 * 1024 * 512 * 2);
  unsigned short* BT_ff1 = (unsigned short*)alloc((size_t)4 * 1024 * 1024 * 2);
  unsigned short* BT_ff2 = (unsigned short*)alloc((size_t)4 * 1024 * 1024 * 2);
  unsigned short* BT_cls = (unsigned short*)alloc((size_t)1024 * 8192 * 2);
  unsigned short* feats  = (unsigned short*)alloc((size_t)256 * 4096 * 2);
  float*          z      = (float*)alloc((size_t)2048 * 1024 * 4);
  unsigned short* h      = (unsigned short*)alloc((size_t)2048 * 1024 * 2);  // also reused as tl
  float*          qkvf   = (float*)alloc((size_t)2048 * 1536 * 4);
  unsigned short* obuf   = (unsigned short*)alloc((size_t)2048 * 512 * 2);
  unsigned short* g      = (unsigned short*)alloc((size_t)2048 * 1024 * 2);
  if ((size_t)(w - (char*)d_ws) > ws_size) return;  // fail visibly rather than corrupt

  dim3 tb(32, 8);
  wcast_t<<<dim3(32, 128, 1), tb, 0, stream>>>(w_img, BT_img, 4096, 1024, 1024);
  wcast_t<<<dim3(48, 32, 4),  tb, 0, stream>>>(w_qkv, BT_qkv, 1024, 1536, 1536);
  wcast_t<<<dim3(32, 16, 4),  tb, 0, stream>>>(w_o,   BT_o,   512, 1024, 1024);
  wcast_t<<<dim3(32, 32, 4),  tb, 0, stream>>>(w_ff1, BT_ff1, 1024, 1024, 1024);
  wcast_t<<<dim3(32, 32, 4),  tb, 0, stream>>>(w_ff2, BT_ff2, 1024, 1024, 1024);
  wcast_t<<<dim3(32, 256, 1), tb, 0, stream>>>(w_cls, BT_cls, 8192, 1000, 1024);

  crop_kernel<<<256, 256, 0, stream>>>(x, tr, feats);
  zinit_kernel<<<1792, 256, 0, stream>>>(hist, z);

  // image_latent -> z[:,7,:]  (outF = z + 7*1024, ldC = 8192)
  gemm64<0, false, false><<<dim3(16, 4), 256, 0, stream>>>(
      feats, BT_img, b_img, nullptr, z + 7168, nullptr, 4096, 8192, 1024);

  for (int i = 0; i < 4; ++i) {
    ln_kernel<<<512, 256, 0, stream>>>(z, ln1_s + i * 1024, ln1_b + i * 1024, h);
    gemm64<0, false, false><<<dim3(24, 32), 256, 0, stream>>>(
        h, BT_qkv + (size_t)i * 1536 * 1024, nullptr, nullptr, qkvf, nullptr, 1024, 1536, 1536);
    attn_kernel<<<2048, 64, 0, stream>>>(qkvf, obuf);
    gemm64<0, false, true><<<dim3(16, 32), 256, 0, stream>>>(
        obuf, BT_o + (size_t)i * 1024 * 512, b_o + i * 1024, z, z, nullptr, 512, 1024, 1024);
    ln_kernel<<<512, 256, 0, stream>>>(z, ln2_s + i * 1024, ln2_b + i * 1024, h);
    gemm64<1, true, false><<<dim3(16, 32), 256, 0, stream>>>(
        h, BT_ff1 + (size_t)i * 1024 * 1024, b_ff1 + i * 1024, nullptr, nullptr, g, 1024, 1024, 1024);
    gemm64<0, false, true><<<dim3(16, 32), 256, 0, stream>>>(
        g, BT_ff2 + (size_t)i * 1024 * 1024, b_ff2 + i * 1024, z, z, nullptr, 1024, 1024, 1024);
  }

  castz_kernel<<<2048, 256, 0, stream>>>(z, h);   // tl (bf16) reuses h
  gemm64<0, false, false><<<dim3(16, 4), 256, 0, stream>>>(
      h, BT_cls, b_cls, nullptr, outF, nullptr, 8192, 1000, 1000);
  trhead_kernel<<<256, 256, 0, stream>>>(z, w_tr, b_tr, outF);
}

// Round 2
// 393.434 us; speedup vs baseline: 1.0907x; 1.0907x over previous
//
#include <hip/hip_runtime.h>
#include <cstdint>
#include <cstddef>

// ---------- types ----------
typedef __attribute__((ext_vector_type(8))) __bf16 bf16x8;
typedef __attribute__((ext_vector_type(4))) float f32x4;
typedef __attribute__((ext_vector_type(4))) unsigned short u16x4;

__device__ __forceinline__ unsigned short f2bf(float f) {
  unsigned int u = __builtin_bit_cast(unsigned int, f);
  u += 0x7fffu + ((u >> 16) & 1u);           // RNE
  return (unsigned short)(u >> 16);
}
__device__ __forceinline__ float bf2f(unsigned short u) {
  return __builtin_bit_cast(float, ((unsigned int)u) << 16);
}

// ---------- batched weight cast + transpose: W[K][N] f32 -> WT[Npad][K] bf16 ----------
// One launch for all 6 weight tensors; per-weight tile ranges are compile-time.
__global__ void wcast_all(const float* __restrict__ s_img, const float* __restrict__ s_qkv,
                          const float* __restrict__ s_o,   const float* __restrict__ s_ff1,
                          const float* __restrict__ s_ff2, const float* __restrict__ s_cls,
                          unsigned short* __restrict__ d_img, unsigned short* __restrict__ d_qkv,
                          unsigned short* __restrict__ d_o,   unsigned short* __restrict__ d_ff1,
                          unsigned short* __restrict__ d_ff2, unsigned short* __restrict__ d_cls) {
  int bid = blockIdx.x;
  const float* src; unsigned short* dst; int K, N, Npad, rel;
  if (bid < 4096)       { src = s_img; dst = d_img; K = 4096; N = 1024; Npad = 1024; rel = bid; }
  else if (bid < 10240) { rel = bid - 4096;  int l = rel / 1536; rel -= l * 1536;
                          src = s_qkv + (size_t)l * 1024 * 1536; dst = d_qkv + (size_t)l * 1536 * 1024;
                          K = 1024; N = 1536; Npad = 1536; }
  else if (bid < 12288) { rel = bid - 10240; int l = rel / 512;  rel -= l * 512;
                          src = s_o   + (size_t)l * 512 * 1024;  dst = d_o   + (size_t)l * 1024 * 512;
                          K = 512;  N = 1024; Npad = 1024; }
  else if (bid < 16384) { rel = bid - 12288; int l = rel / 1024; rel -= l * 1024;
                          src = s_ff1 + (size_t)l * 1024 * 1024; dst = d_ff1 + (size_t)l * 1024 * 1024;
                          K = 1024; N = 1024; Npad = 1024; }
  else if (bid < 20480) { rel = bid - 16384; int l = rel / 1024; rel -= l * 1024;
                          src = s_ff2 + (size_t)l * 1024 * 1024; dst = d_ff2 + (size_t)l * 1024 * 1024;
                          K = 1024; N = 1024; Npad = 1024; }
  else                  { rel = bid - 20480; src = s_cls; dst = d_cls; K = 8192; N = 1000; Npad = 1024; }
  int tilesX = Npad >> 5;
  int nx = rel % tilesX, ky = rel / tilesX;
  int n0 = nx * 32, k0 = ky * 32;
  __shared__ float tile[32][33];
  int tx = threadIdx.x, ty = threadIdx.y;
#pragma unroll
  for (int i = ty; i < 32; i += 8) {
    int k = k0 + i, n = n0 + tx;
    tile[i][tx] = (n < N) ? src[(size_t)k * N + n] : 0.0f;
  }
  __syncthreads();
#pragma unroll
  for (int i = ty; i < 32; i += 8) {
    int n = n0 + i, k = k0 + tx;
    dst[(size_t)n * K + k] = f2bf(tile[tx][i]);
  }
}

// ---------- crop + *128 -> feats bf16 [256][4096] ----------
__global__ void crop_kernel(const float* __restrict__ x, const float* __restrict__ tr,
                            unsigned short* __restrict__ feats) {
  int b = blockIdx.x;
  __shared__ int xi[64], yi[64];
  float px = tr[b * 4 + 0], py = tr[b * 4 + 1], zx = tr[b * 4 + 2], zy = tr[b * 4 + 3];
  float x1 = __fmul_rn(px, 448.0f);
  float y1 = __fmul_rn(py, 448.0f);
  float xs = fminf(__fsub_rn(512.0f, x1), __fadd_rn(__fmul_rn(zx, 448.0f), 64.0f));
  float ys = fminf(__fsub_rn(512.0f, y1), __fadd_rn(__fmul_rn(zy, 448.0f), 64.0f));
  int t = threadIdx.x;
  if (t < 64) {
    float u = __fmul_rn(__fmul_rn((float)t, 0.015625f), xs);
    int v = (int)(__fadd_rn(floorf(u), x1));
    xi[t] = min(max(v, 0), 511);
  } else if (t < 128) {
    int tt = t - 64;
    float u = __fmul_rn(__fmul_rn((float)tt, 0.015625f), ys);
    int v = (int)(__fadd_rn(floorf(u), y1));
    yi[tt] = min(max(v, 0), 511);
  }
  __syncthreads();
  const float* img = x + (size_t)b * 262144;
  for (int p = t; p < 4096; p += 256) {
    int i = p >> 6, j = p & 63;
    float val = img[xi[i] * 512 + yi[j]] * 128.0f;
    feats[(size_t)b * 4096 + p] = f2bf(val);
  }
}

// ---------- z init: z[b][i][:] = history[i+1][b][:] for i<7 ----------
__global__ void zinit_kernel(const float* __restrict__ hist, float* __restrict__ z) {
  int idx = blockIdx.x * 256 + threadIdx.x;
  int off = idx * 4;
  int b = off / 7168;
  int r = off - b * 7168;
  int i = r >> 10, c = r & 1023;
  float4 v = *(const float4*)(hist + (size_t)(i + 1) * 262144 + (size_t)b * 1024 + c);
  *(float4*)(z + (size_t)b * 8192 + i * 1024 + c) = v;
}

// ---------- LayerNorm: z f32 [2048][1024] -> h bf16 (wave per row) ----------
__global__ __launch_bounds__(256) void ln_kernel(const float* __restrict__ z,
                                                 const float* __restrict__ sc,
                                                 const float* __restrict__ bi,
                                                 unsigned short* __restrict__ h) {
  int row = blockIdx.x * 4 + (threadIdx.x >> 6);
  int lane = threadIdx.x & 63;
  const float* zr = z + (size_t)row * 1024;
  float4 v[4];
  float s = 0.f, q = 0.f;
#pragma unroll
  for (int i = 0; i < 4; i++) {
    v[i] = *(const float4*)(zr + lane * 4 + i * 256);
    s += v[i].x + v[i].y + v[i].z + v[i].w;
    q += v[i].x * v[i].x + v[i].y * v[i].y + v[i].z * v[i].z + v[i].w * v[i].w;
  }
#pragma unroll
  for (int off = 32; off; off >>= 1) { s += __shfl_xor(s, off); q += __shfl_xor(q, off); }
  float mean = s * (1.0f / 1024.0f);
  float var = q * (1.0f / 1024.0f) - mean * mean;
  float rstd = rsqrtf(var + 1e-5f);
  u16x4* out = (u16x4*)(h + (size_t)row * 1024);
#pragma unroll
  for (int i = 0; i < 4; i++) {
    int c = lane * 4 + i * 256;
    float4 sv = *(const float4*)(sc + c);
    float4 bv = *(const float4*)(bi + c);
    u16x4 o;
    o.x = f2bf((v[i].x - mean) * rstd * sv.x + bv.x);
    o.y = f2bf((v[i].y - mean) * rstd * sv.y + bv.y);
    o.z = f2bf((v[i].z - mean) * rstd * sv.z + bv.z);
    o.w = f2bf((v[i].w - mean) * rstd * sv.w + bv.w);
    out[lane + i * 64] = o;
  }
}

// ---------- tiny attention: per (b,head), S=8, D=64, bf16 in/out ----------
__global__ __launch_bounds__(64) void attn_kernel(const unsigned short* __restrict__ qkv,
                                                  unsigned short* __restrict__ obuf) {
  int bh = blockIdx.x;
  int b = bh >> 3, hh = bh & 7;
  const unsigned short* base = qkv + (size_t)b * 8 * 1536;
  __shared__ float Q[8][64], K[8][64], V[8][64], S[8][8], P[8][8];
  int t = threadIdx.x;
#pragma unroll
  for (int i = 0; i < 8; i++) {
    Q[i][t] = bf2f(base[i * 1536 + hh * 64 + t]);
    K[i][t] = bf2f(base[i * 1536 + 512 + hh * 64 + t]);
    V[i][t] = bf2f(base[i * 1536 + 1024 + hh * 64 + t]);
  }
  __syncthreads();
  {
    int i = t >> 3, j = t & 7;
    float s = 0.f;
#pragma unroll
    for (int d = 0; d < 64; d++) s += Q[i][d] * K[j][d];
    S[i][j] = s * 0.125f;
  }
  __syncthreads();
  {
    int i = t >> 3, j = t & 7;
    float m = S[i][0];
#pragma unroll
    for (int jj = 1; jj < 8; jj++) m = fmaxf(m, S[i][jj]);
    float sum = 0.f;
#pragma unroll
    for (int jj = 0; jj < 8; jj++) sum += expf(S[i][jj] - m);
    P[i][j] = expf(S[i][j] - m) / sum;
  }
  __syncthreads();
#pragma unroll
  for (int i = 0; i < 8; i++) {
    float o = 0.f;
#pragma unroll
    for (int j = 0; j < 8; j++) o += P[i][j] * V[j][t];
    obuf[(size_t)(b * 8 + i) * 512 + hh * 64 + t] = f2bf(o);
  }
}

// ---------- bf16 MFMA GEMM, 128x64 tile, BK=64, 4 waves ----------
template <int ITERS>
__device__ __forceinline__ void stage_tile(const unsigned short* __restrict__ g, int ld,
                                           int k0, char* lbase, int tid) {
#pragma unroll
  for (int it = 0; it < ITERS; ++it) {
    int c = tid + it * 256;              // 16B chunk id; 8 chunks per 64-k row
    int r = c >> 3;
    int c8 = (c & 7) ^ (r & 7);          // pre-swizzled global source (m173 pattern)
    const unsigned short* src = g + (size_t)r * ld + (k0 + c8 * 8);
    char* dst = lbase + c * 16;          // linear LDS dest: base + lane*16
    __builtin_amdgcn_global_load_lds((__attribute__((address_space(1))) void*)src,
                                     (__attribute__((address_space(3))) void*)dst, 16, 0, 0);
  }
}

__device__ __forceinline__ bf16x8 ld_frag(const char* base, int row, int k8) {
  int off = (row << 7) + ((k8 ^ (row & 7)) << 4);   // XOR swizzle (G4)
  return *(const bf16x8*)(base + off);
}

template <int ACT, bool OBF, bool RES>
__global__ __launch_bounds__(256) void gemm128(
    const unsigned short* __restrict__ A, int lda,
    const unsigned short* __restrict__ BT, int ldb,
    int Kloop, const float* __restrict__ bias, const float* __restrict__ res,
    float* __restrict__ outF, unsigned short* __restrict__ outB,
    int ldC, int Nstore, int partStride) {
  __shared__ __align__(16) char smem[2][24576];   // A 16KB + B 8KB per buffer
  const int tid = threadIdx.x;
  const int lane = tid & 63;
  const int wid = tid >> 6;                        // wave owns rows [wid*32, wid*32+32)
  const int m0 = blockIdx.y << 7, n0 = blockIdx.x << 6;
  const int koff = blockIdx.z * Kloop;
  const unsigned short* Ag = A + (size_t)m0 * lda + koff;
  const unsigned short* Bg = BT + (size_t)n0 * ldb + koff;
  float* outFb = outF ? outF + (size_t)blockIdx.z * partStride : outF;
  f32x4 acc[2][4];
#pragma unroll
  for (int m = 0; m < 2; m++)
#pragma unroll
    for (int n = 0; n < 4; n++) acc[m][n] = 0.f;
  const int nt = Kloop >> 6;
  stage_tile<4>(Ag, lda, 0, smem[0], tid);
  stage_tile<2>(Bg, ldb, 0, smem[0] + 16384, tid);
  __syncthreads();
  int cur = 0;
  const int rA = lane & 15, kq = lane >> 4;
  for (int t = 0; t < nt; ++t) {
    if (t + 1 < nt) {
      stage_tile<4>(Ag, lda, (t + 1) << 6, smem[cur ^ 1], tid);
      stage_tile<2>(Bg, ldb, (t + 1) << 6, smem[cur ^ 1] + 16384, tid);
    }
    const char* la = smem[cur];
    const char* lb = smem[cur] + 16384;
#pragma unroll
    for (int kk = 0; kk < 2; ++kk) {
      int k8 = kk * 4 + kq;
      bf16x8 a0 = ld_frag(la, wid * 32 + rA, k8);
      bf16x8 a1 = ld_frag(la, wid * 32 + 16 + rA, k8);
      bf16x8 b0 = ld_frag(lb, rA, k8);
      bf16x8 b1 = ld_frag(lb, 16 + rA, k8);
      bf16x8 b2 = ld_frag(lb, 32 + rA, k8);
      bf16x8 b3 = ld_frag(lb, 48 + rA, k8);
      acc[0][0] = __builtin_amdgcn_mfma_f32_16x16x32_bf16(a0, b0, acc[0][0], 0, 0, 0);
      acc[0][1] = __builtin_amdgcn_mfma_f32_16x16x32_bf16(a0, b1, acc[0][1], 0, 0, 0);
      acc[0][2] = __builtin_amdgcn_mfma_f32_16x16x32_bf16(a0, b2, acc[0][2], 0, 0, 0);
      acc[0][3] = __builtin_amdgcn_mfma_f32_16x16x32_bf16(a0, b3, acc[0][3], 0, 0, 0);
      acc[1][0] = __builtin_amdgcn_mfma_f32_16x16x32_bf16(a1, b0, acc[1][0], 0, 0, 0);
      acc[1][1] = __builtin_amdgcn_mfma_f32_16x16x32_bf16(a1, b1, acc[1][1], 0, 0, 0);
      acc[1][2] = __builtin_amdgcn_mfma_f32_16x16x32_bf16(a1, b2, acc[1][2], 0, 0, 0);
      acc[1][3] = __builtin_amdgcn_mfma_f32_16x16x32_bf16(a1, b3, acc[1][3], 0, 0, 0);
    }
    __syncthreads();
    cur ^= 1;
  }
  const int rb = m0 + wid * 32 + (kq << 2);
  const int cb = n0 + rA;
#pragma unroll
  for (int m = 0; m < 2; m++)
#pragma unroll
    for (int n = 0; n < 4; n++) {
      int cg = cb + n * 16;
      if (cg >= Nstore) continue;
      float bv = bias ? bias[cg] : 0.0f;
#pragma unroll
      for (int j = 0; j < 4; j++) {
        int rg = rb + m * 16 + j;
        float v = acc[m][n][j] + bv;
        if (RES) v += res[(size_t)rg * ldC + cg];
        if (ACT == 1) v = 0.5f * v * (1.0f + erff(v * 0.70710678118654752f));
        if (OBF) outB[(size_t)rg * ldC + cg] = f2bf(v);
        else outFb[(size_t)rg * ldC + cg] = v;
      }
    }
}

// ---------- split-K reduce: sum partials [nparts][256][1024] + bias -> dst ----------
__global__ __launch_bounds__(256) void reduceK(const float* __restrict__ part, int partStride,
                                               int nparts, const float* __restrict__ bias,
                                               float* __restrict__ dst, int ldDst, int Nstore) {
  int m = blockIdx.x;
  int c = threadIdx.x * 4;
  float4 a = {0.f, 0.f, 0.f, 0.f};
  for (int p = 0; p < nparts; ++p) {
    float4 v = *(const float4*)(part + (size_t)p * partStride + m * 1024 + c);
    a.x += v.x; a.y += v.y; a.z += v.z; a.w += v.w;
  }
  float4 bv = *(const float4*)(bias + c);
  a.x += bv.x; a.y += bv.y; a.z += bv.z; a.w += bv.w;
  if (c >= Nstore) return;
  float* drow = dst + (size_t)m * ldDst;
  if (c + 3 < Nstore) {
    *(float4*)(drow + c) = a;
  } else {
    float vals[4] = {a.x, a.y, a.z, a.w};
    for (int i = 0; i < 4 && c + i < Nstore; ++i) drow[c + i] = vals[i];
  }
}

// ---------- z f32 -> bf16 cast ----------
__global__ void castz_kernel(const float* __restrict__ z, unsigned short* __restrict__ tl) {
  int i = blockIdx.x * 256 + threadIdx.x;
  float4 v = *(const float4*)(z + (size_t)i * 4);
  u16x4 o;
  o.x = f2bf(v.x); o.y = f2bf(v.y); o.z = f2bf(v.z); o.w = f2bf(v.w);
  *(u16x4*)(tl + (size_t)i * 4) = o;
}

// ---------- transform head: sigmoid(z_flat @ w_tr + b_tr), N=4, K=8192 ----------
__global__ __launch_bounds__(256) void trhead_kernel(const float* __restrict__ z,
                                                     const float* __restrict__ w,
                                                     const float* __restrict__ bt,
                                                     float* __restrict__ out) {
  int b = blockIdx.x;
  int t = threadIdx.x;
  const float* row = z + (size_t)b * 8192;
  float a0 = 0.f, a1 = 0.f, a2 = 0.f, a3 = 0.f;
  for (int k = t; k < 8192; k += 256) {
    float xv = row[k];
    const float* wr = w + (size_t)k * 4;
    a0 += xv * wr[0]; a1 += xv * wr[1]; a2 += xv * wr[2]; a3 += xv * wr[3];
  }
  __shared__ float red[256][4];
  red[t][0] = a0; red[t][1] = a1; red[t][2] = a2; red[t][3] = a3;
  __syncthreads();
  for (int s = 128; s > 0; s >>= 1) {
    if (t < s) {
#pragma unroll
      for (int o = 0; o < 4; o++) red[t][o] += red[t + s][o];
    }
    __syncthreads();
  }
  if (t < 4) {
    float v = red[0][t] + bt[t];
    out[256000 + b * 4 + t] = 1.0f / (1.0f + expf(-v));
  }
}

// ---------- launch ----------
extern "C" void kernel_launch(void* const* d_in, const int* in_sizes, int n_in,
                              void* d_out, int out_size, void* d_ws, size_t ws_size,
                              hipStream_t stream) {
  const float* x      = (const float*)d_in[0];
  const float* tr     = (const float*)d_in[1];
  const float* hist   = (const float*)d_in[2];
  const float* w_img  = (const float*)d_in[3];
  const float* b_img  = (const float*)d_in[4];
  const float* ln1_s  = (const float*)d_in[5];
  const float* ln1_b  = (const float*)d_in[6];
  const float* w_qkv  = (const float*)d_in[7];
  const float* w_o    = (const float*)d_in[8];
  const float* b_o    = (const float*)d_in[9];
  const float* ln2_s  = (const float*)d_in[10];
  const float* ln2_b  = (const float*)d_in[11];
  const float* w_ff1  = (const float*)d_in[12];
  const float* b_ff1  = (const float*)d_in[13];
  const float* w_ff2  = (const float*)d_in[14];
  const float* b_ff2  = (const float*)d_in[15];
  const float* w_cls  = (const float*)d_in[16];
  const float* b_cls  = (const float*)d_in[17];
  const float* w_tr   = (const float*)d_in[18];
  const float* b_tr   = (const float*)d_in[19];
  float* outF = (float*)d_out;

  char* w = (char*)d_ws;
  auto alloc = [&](size_t bytes) { char* p = w; w += (bytes + 255) & ~(size_t)255; return p; };
  unsigned short* BT_img = (unsigned short*)alloc((size_t)1024 * 4096 * 2);
  unsigned short* BT_qkv = (unsigned short*)alloc((size_t)4 * 1536 * 1024 * 2);
  unsigned short* BT_o   = (unsigned short*)alloc((size_t)4 * 1024 * 512 * 2);
  unsigned short* BT_ff1 = (unsigned short*)alloc((size_t)4 * 1024 * 1024 * 2);
  unsigned short* BT_ff2 = (unsigned short*)alloc((size_t)4 * 1024 * 1024 * 2);
  unsigned short* BT_cls = (unsigned short*)alloc((size_t)1024 * 8192 * 2);
  unsigned short* feats  = (unsigned short*)alloc((size_t)256 * 4096 * 2);
  float*          z      = (float*)alloc((size_t)2048 * 1024 * 4);
  unsigned short* h      = (unsigned short*)alloc((size_t)2048 * 1024 * 2);  // also tl
  unsigned short* qkvb   = (unsigned short*)alloc((size_t)2048 * 1536 * 2);
  unsigned short* obuf   = (unsigned short*)alloc((size_t)2048 * 512 * 2);
  unsigned short* g      = (unsigned short*)alloc((size_t)2048 * 1024 * 2);
  float*          part   = (float*)alloc((size_t)8 * 256 * 1024 * 4);
  if ((size_t)(w - (char*)d_ws) > ws_size) return;

  wcast_all<<<28672, dim3(32, 8), 0, stream>>>(w_img, w_qkv, w_o, w_ff1, w_ff2, w_cls,
                                               BT_img, BT_qkv, BT_o, BT_ff1, BT_ff2, BT_cls);
  crop_kernel<<<256, 256, 0, stream>>>(x, tr, feats);
  zinit_kernel<<<1792, 256, 0, stream>>>(hist, z);

  // image_latent: [256,4096]@[4096,1024] split-K x8 (Kc=512) -> part -> z[:,7,:]
  gemm128<0, false, false><<<dim3(16, 2, 8), 256, 0, stream>>>(
      feats, 4096, BT_img, 4096, 512, nullptr, nullptr, part, nullptr, 1024, 1024, 262144);
  reduceK<<<256, 256, 0, stream>>>(part, 262144, 8, b_img, z + 7168, 8192, 1024);

  for (int i = 0; i < 4; ++i) {
    ln_kernel<<<512, 256, 0, stream>>>(z, ln1_s + i * 1024, ln1_b + i * 1024, h);
    gemm128<0, true, false><<<dim3(24, 16), 256, 0, stream>>>(
        h, 1024, BT_qkv + (size_t)i * 1536 * 1024, 1024, 1024,
        nullptr, nullptr, nullptr, qkvb, 1536, 1536, 0);
    attn_kernel<<<2048, 64, 0, stream>>>(qkvb, obuf);
    gemm128<0, false, true><<<dim3(16, 16), 256, 0, stream>>>(
        obuf, 512, BT_o + (size_t)i * 1024 * 512, 512, 512,
        b_o + i * 1024, z, z, nullptr, 1024, 1024, 0);
    ln_kernel<<<512, 256, 0, stream>>>(z, ln2_s + i * 1024, ln2_b + i * 1024, h);
    gemm128<1, true, false><<<dim3(16, 16), 256, 0, stream>>>(
        h, 1024, BT_ff1 + (size_t)i * 1024 * 1024, 1024, 1024,
        b_ff1 + i * 1024, nullptr, nullptr, g, 1024, 1024, 0);
    gemm128<0, false, true><<<dim3(16, 16), 256, 0, stream>>>(
        g, 1024, BT_ff2 + (size_t)i * 1024 * 1024, 1024, 1024,
        b_ff2 + i * 1024, z, z, nullptr, 1024, 1024, 0);
  }

  castz_kernel<<<2048, 256, 0, stream>>>(z, h);   // tl (bf16) reuses h
  // cls: [256,8192]@[8192,1024pad] split-K x8 (Kc=1024) -> part -> outF[:,:1000]
  gemm128<0, false, false><<<dim3(16, 2, 8), 256, 0, stream>>>(
      h, 8192, BT_cls, 8192, 1024, nullptr, nullptr, part, nullptr, 1024, 1024, 262144);
  reduceK<<<256, 256, 0, stream>>>(part, 262144, 8, b_cls, outF, 1000, 1000);
  trhead_kernel<<<256, 256, 0, stream>>>(z, w_tr, b_tr, outF);
}